// Round 10
// baseline (232.376 us; speedup 1.0000x reference)
//
#include <hip/hip_runtime.h>

#define B_ 8
#define L_ 2048
#define E_ 256
#define H_ 4
#define D_ 64

typedef __bf16 bf16;
typedef __bf16 bf16x8 __attribute__((ext_vector_type(8)));
typedef __bf16 bf16x4 __attribute__((ext_vector_type(4)));
typedef float  f32x4  __attribute__((ext_vector_type(4)));
typedef float  f32x16 __attribute__((ext_vector_type(16)));

// Ŝ = (q·k)/8 * log2(e); softmax entirely in exp2 domain.
#define QSCALE 0.1803368801111244f

__device__ __forceinline__ float fexp2(float x) { return __builtin_amdgcn_exp2f(x); }
__device__ __forceinline__ float flog2(float x) { return __builtin_amdgcn_logf(x); }

// Barrier that drains LDS ops but NOT global loads (vmcnt stays in flight).
// Safe when all cross-wave communication is through LDS.
__device__ __forceinline__ void barrier_lds() {
    asm volatile("s_waitcnt lgkmcnt(0)" ::: "memory");
    __builtin_amdgcn_s_barrier();
}

// ---------------------------------------------------------------------------
// Kernel 0 (fused): blocks 0..4095 convert x -> bf16 xb [B,L,E];
// blocks 4096..4863 repack weights -> Wcat[768][256].
// ---------------------------------------------------------------------------
__global__ void prep_kernel(const float* __restrict__ x,
                            const float* __restrict__ in_proj_w,
                            const float* __restrict__ W_gnn,
                            bf16* __restrict__ xb, bf16* __restrict__ Wcat) {
    int bid = blockIdx.x;
    if (bid < 4096) {
        size_t i = ((size_t)bid * 256 + threadIdx.x) * 4;
        f32x4 v = *(const f32x4*)&x[i];
        bf16x4 o;
#pragma unroll
        for (int j = 0; j < 4; j++) o[j] = (bf16)v[j];
        *(bf16x4*)&xb[i] = o;
    } else {
        int r = bid - 4096;
        int e = threadIdx.x;
        float v = (r < 512) ? in_proj_w[r * E_ + e] : W_gnn[e * E_ + (r - 512)];
        Wcat[r * E_ + e] = (bf16)v;
    }
}

// ---------------------------------------------------------------------------
// Kernel 2: projections. C[M=16384, N=768] = x @ Wcat^T (bf16 MFMA, fp32 acc)
//   by==0 -> Qs ; by==1 -> Ks ; by==2 -> XWT[B,E,L]
// (256,2): r8 measured (256,4) costs ~10us (VGPR cap throttles staging).
// ---------------------------------------------------------------------------
__global__ __launch_bounds__(256, 2) void proj_kernel(
    const bf16* __restrict__ xb, const bf16* __restrict__ Wcat,
    const float* __restrict__ in_proj_b, const float* __restrict__ B_gnn,
    bf16* __restrict__ Qs, bf16* __restrict__ Ks, bf16* __restrict__ XWT) {
    int tid  = threadIdx.x;
    int lane = tid & 63, wave = tid >> 6;
    int l16  = lane & 15, quad = lane >> 4;
    int m0 = blockIdx.x * 64 + wave * 16;
    int by = blockIdx.y;
    int n0 = by * 256;

    f32x4 acc[16];
#pragma unroll
    for (int i = 0; i < 16; i++) acc[i] = (f32x4){0.f, 0.f, 0.f, 0.f};

    const bf16* xrow = xb + (size_t)(m0 + l16) * E_;
    for (int ks = 0; ks < 8; ks++) {
        int koff = ks * 32 + quad * 8;
        bf16x8 af = *(const bf16x8*)&xrow[koff];
#pragma unroll
        for (int nt = 0; nt < 16; nt++) {
            bf16x8 bfv = *(const bf16x8*)&Wcat[(size_t)(n0 + nt * 16 + l16) * E_ + koff];
            acc[nt] = __builtin_amdgcn_mfma_f32_16x16x32_bf16(af, bfv, acc[nt], 0, 0, 0);
        }
    }

#pragma unroll
    for (int nt = 0; nt < 16; nt++) {
        int n = n0 + nt * 16 + l16;
        if (by == 0) {
            float bias = in_proj_b[n];
#pragma unroll
            for (int r = 0; r < 4; r++) {
                int m = m0 + quad * 4 + r;
                Qs[(size_t)m * E_ + n] = (bf16)((acc[nt][r] + bias) * QSCALE);
            }
        } else if (by == 1) {
            float bias = in_proj_b[n];
            int col = n - 256;
#pragma unroll
            for (int r = 0; r < 4; r++) {
                int m = m0 + quad * 4 + r;
                Ks[(size_t)m * E_ + col] = (bf16)(acc[nt][r] + bias);
            }
        } else {
            int nc = n - 512;
            float bias = B_gnn[nc];
            int m = m0 + quad * 4;
            int b = m >> 11, l = m & 2047;
            bf16x4 pk;
#pragma unroll
            for (int r = 0; r < 4; r++) pk[r] = (bf16)(acc[nt][r] + bias);
            *(bf16x4*)&XWT[((size_t)b * E_ + nc) * L_ + l] = pk;
        }
    }
}

// ---------------------------------------------------------------------------
// Kernel 3: softmax stats (r7 version: dbuf ldsK, 1 lgkm barrier/iter).
// ---------------------------------------------------------------------------
__global__ __launch_bounds__(256, 4) void stats_kernel(
    const bf16* __restrict__ Qs, const bf16* __restrict__ Ks,
    float* __restrict__ o) {
    __shared__ bf16 ldsK[2][64 * 72];
    int tid  = threadIdx.x;
    int lane = tid & 63, wave = tid >> 6;
    int r32  = lane & 31, half = lane >> 5;
    int qt = blockIdx.x, h = blockIdx.y, b = blockIdx.z;
    int q0 = qt * 128 + wave * 32;

    bf16x8 qa[4];
    const bf16* qrow = Qs + ((size_t)b * L_ + q0 + r32) * E_ + h * D_;
#pragma unroll
    for (int c = 0; c < 4; c++) qa[c] = *(const bf16x8*)&qrow[c * 16 + half * 8];

    float lsum[16];
#pragma unroll
    for (int i = 0; i < 16; i++) lsum[i] = 0.f;

    const bf16* Kb = Ks + (size_t)b * L_ * E_ + h * D_;

#pragma unroll
    for (int it = 0; it < 2; it++) {
        int idx = it * 256 + tid;
        int key = idx >> 3, dc = (idx & 7) * 8;
        *(bf16x8*)&ldsK[0][key * 72 + dc] =
            *(const bf16x8*)&Kb[(size_t)key * E_ + dc];
    }
    __syncthreads();

    int cur = 0;
    for (int kt = 0; kt < 32; kt++) {
        bf16x8 pk0, pk1;
        if (kt < 31) {
            int idx0 = tid, idx1 = 256 + tid;
            pk0 = *(const bf16x8*)&Kb[(size_t)((kt + 1) * 64 + (idx0 >> 3)) * E_ + (idx0 & 7) * 8];
            pk1 = *(const bf16x8*)&Kb[(size_t)((kt + 1) * 64 + (idx1 >> 3)) * E_ + (idx1 & 7) * 8];
        }
#pragma unroll
        for (int nt = 0; nt < 2; nt++) {
            f32x16 S = {};
#pragma unroll
            for (int c = 0; c < 4; c++) {
                bf16x8 kb = *(const bf16x8*)&ldsK[cur][(nt * 32 + r32) * 72 + c * 16 + half * 8];
                S = __builtin_amdgcn_mfma_f32_32x32x16_bf16(qa[c], kb, S, 0, 0, 0);
            }
#pragma unroll
            for (int i = 0; i < 16; i++) lsum[i] += fexp2(S[i]);
        }
        if (kt < 31) {
            int idx0 = tid, idx1 = 256 + tid;
            *(bf16x8*)&ldsK[cur ^ 1][(idx0 >> 3) * 72 + (idx0 & 7) * 8] = pk0;
            *(bf16x8*)&ldsK[cur ^ 1][(idx1 >> 3) * 72 + (idx1 & 7) * 8] = pk1;
        }
        barrier_lds();
        cur ^= 1;
    }
#pragma unroll
    for (int i = 0; i < 16; i++) {
        float v = lsum[i];
        v += __shfl_xor(v, 1); v += __shfl_xor(v, 2); v += __shfl_xor(v, 4);
        v += __shfl_xor(v, 8); v += __shfl_xor(v, 16);
        lsum[i] = v;
    }
    if (r32 == 0) {
        float* op = o + ((size_t)(b * H_ + h)) * L_ + q0;
#pragma unroll
        for (int i = 0; i < 16; i++) {
            int row = (i & 3) + 8 * (i >> 2) + 4 * half;
            op[row] = -(2.0f + flog2(lsum[i]));
        }
    }
}

// ---------------------------------------------------------------------------
// Kernel 4: pass 2, PV-lag-1 pipeline, 8-wave (512-thr) blocks, 128 q/block.
// Waves: QK role (qh=w&3, kh=w>>2): S^T[32k x 32q] quadrant; PV role
// (qh, nh=kh): O[32q x 128n] over 64k, LAGGED one iteration so PV_{k-1}
// interleaves with QK_k in the same barrier interval (breaks the pipe
// lockstep that made r9's pass2 = LDS+VALU+MFMA serialized sum).
// Buffers: tile t -> buf t&1. ldsK single (QK-only), ldsXW/ldsP double.
// Per iter: issue loads(k+1) | QK_k -> P | PV_{k-1} | P->ldsP[bk] |
//   BARRIER1 (drains ldsK reads, xw/p prev reads) | write prefetch ->
//   ldsK + ldsXW[bk^1] (vmcnt lands here, ~full iter after issue) |
//   BARRIER2 (publish tile k+1 + P_k). Epilogue: PV_15.
// LDS 144.4 KB -> 1 block/CU (8 waves = 2/SIMD, same as r9).
// ---------------------------------------------------------------------------
__global__ __launch_bounds__(512, 2) void pass2_kernel(
    const bf16* __restrict__ Qs, const bf16* __restrict__ Ks,
    const bf16* __restrict__ XWT, const float* __restrict__ o,
    float* __restrict__ Opart) {
    __shared__ alignas(16) unsigned char smem[144384];
    bf16* ldsK   = (bf16*)smem;              // [64 keys][264]   33792 B
    bf16* ldsXW0 = (bf16*)(smem + 33792);    // [256 n][72]      36864 B
    bf16* ldsXW1 = (bf16*)(smem + 70656);    // [256 n][72]      36864 B
    bf16* ldsP0  = (bf16*)(smem + 107520);   // [128 q][72]      18432 B
    bf16* ldsP1  = (bf16*)(smem + 125952);   // [128 q][72]      18432 B

    int tid  = threadIdx.x;
    int lane = tid & 63, wave = tid >> 6;
    int l32  = lane & 31, half = lane >> 5;
    int qh = wave & 3, kh = wave >> 2;   // QK: q-quarter, k-half
    int nh = kh;                          // PV: n-half

    int flat = blockIdx.x;
    int b   = flat & 7;                  // batch == XCD (L2 pin)
    int qt  = (flat >> 3) & 15;          // 0..15, 128 q each
    int ksp = flat >> 7;                 // 0..1

    int qw = qt * 128 + qh * 32 + l32;

    // Q B-frags, all 4 heads (B-layout: n=lane&31=q, k=(lane>>5)*8+j)
    bf16x8 qf[4][4];
    const bf16* qrow = Qs + ((size_t)b * L_ + qw) * E_;
#pragma unroll
    for (int h = 0; h < H_; h++)
#pragma unroll
        for (int c = 0; c < 4; c++)
            qf[h][c] = *(const bf16x8*)&qrow[h * 64 + c * 16 + half * 8];

    float oh[4];
#pragma unroll
    for (int h = 0; h < H_; h++)
        oh[h] = o[((size_t)(b * H_ + h)) * L_ + qw];

    f32x16 zero = {};
    f32x16 acc[4];
#pragma unroll
    for (int i = 0; i < 4; i++) acc[i] = zero;

    const bf16* Kb = Ks + (size_t)b * L_ * E_;
    const bf16* Xb = XWT + (size_t)b * E_ * L_;

    // prologue: stage tile 0 -> ldsK + ldsXW0
    {
        int k0 = ksp * 1024;
#pragma unroll
        for (int it = 0; it < 4; it++) {
            int idx = it * 512 + tid;
            int key = idx >> 5, col = (idx & 31) * 8;
            *(bf16x8*)&ldsK[key * 264 + col] =
                *(const bf16x8*)&Kb[(size_t)(k0 + key) * E_ + col];
        }
#pragma unroll
        for (int it = 0; it < 4; it++) {
            int idx = it * 512 + tid;
            int n = idx >> 3, kc8 = (idx & 7) * 8;
            *(bf16x8*)&ldsXW0[n * 72 + kc8] =
                *(const bf16x8*)&Xb[(size_t)n * L_ + k0 + kc8];
        }
    }
    __syncthreads();

    for (int kt = 0; kt < 16; kt++) {
        int bk = kt & 1;
        bf16* pcur   = bk ? ldsP1  : ldsP0;   // P_kt written here
        bf16* pprev  = bk ? ldsP0  : ldsP1;   // P_{kt-1} for PV
        bf16* xwprev = bk ? ldsXW0 : ldsXW1;  // tile kt-1 for PV; reused for kt+1

        // issue tile kt+1 loads (stay in flight across both barriers)
        bf16x8 pkf[4], pxf[4];
        if (kt < 15) {
            int k1 = ksp * 1024 + (kt + 1) * 64;
#pragma unroll
            for (int it = 0; it < 4; it++) {
                int idx = it * 512 + tid;
                int key = idx >> 5, col = (idx & 31) * 8;
                pkf[it] = *(const bf16x8*)&Kb[(size_t)(k1 + key) * E_ + col];
            }
#pragma unroll
            for (int it = 0; it < 4; it++) {
                int idx = it * 512 + tid;
                int n = idx >> 3, kc8 = (idx & 7) * 8;
                pxf[it] = *(const bf16x8*)&Xb[(size_t)n * L_ + k1 + kc8];
            }
        }

        // QK_kt: S^T quadrant per head; P = sum_h exp2(S^T + o_h)
        f32x16 P = zero;
#pragma unroll
        for (int h = 0; h < H_; h++) {
            f32x16 s = zero;
#pragma unroll
            for (int c = 0; c < 4; c++) {
                bf16x8 ka = *(const bf16x8*)&ldsK[(kh * 32 + l32) * 264 + h * 64 + c * 16 + half * 8];
                s = __builtin_amdgcn_mfma_f32_32x32x16_bf16(ka, qf[h][c], s, 0, 0, 0);
            }
#pragma unroll
            for (int r = 0; r < 16; r++) P[r] += fexp2(s[r] + oh[h]);
        }

        // PV_{kt-1}: independent of QK_kt -> scheduler interleaves
        if (kt > 0) {
#pragma unroll
            for (int kc = 0; kc < 4; kc++) {
                bf16x8 pa = *(const bf16x8*)&pprev[(qh * 32 + l32) * 72 + kc * 16 + half * 8];
#pragma unroll
                for (int nt = 0; nt < 4; nt++) {
                    bf16x8 xw = *(const bf16x8*)&xwprev[(nh * 128 + nt * 32 + l32) * 72 + kc * 16 + half * 8];
                    acc[nt] = __builtin_amdgcn_mfma_f32_32x32x16_bf16(pa, xw, acc[nt], 0, 0, 0);
                }
            }
        }

        // publish P_kt at TRUE key indices (regs 4g..4g+3 -> keys 8g+4*half+0..3)
#pragma unroll
        for (int g = 0; g < 4; g++) {
            bf16x4 pk;
#pragma unroll
            for (int j = 0; j < 4; j++) pk[j] = (bf16)P[4 * g + j];
            *(bf16x4*)&pcur[(qh * 32 + l32) * 72 + kh * 32 + g * 8 + half * 4] = pk;
        }
        barrier_lds();   // B1: ldsK reads, xwprev/pprev reads, P writes drained

        if (kt < 15) {
            // tile kt+1 -> ldsK and xwprev (the buffer PV just vacated);
            // the only vmcnt wait lands here, ~full iteration after issue
#pragma unroll
            for (int it = 0; it < 4; it++) {
                int idx = it * 512 + tid;
                int key = idx >> 5, col = (idx & 31) * 8;
                *(bf16x8*)&ldsK[key * 264 + col] = pkf[it];
            }
#pragma unroll
            for (int it = 0; it < 4; it++) {
                int idx = it * 512 + tid;
                int n = idx >> 3, kc8 = (idx & 7) * 8;
                *(bf16x8*)&xwprev[n * 72 + kc8] = pxf[it];
            }
            barrier_lds();   // B2: tile kt+1 + P_kt published
        }
    }

    // epilogue: PV_15 (P_15 in ldsP1, tile 15 in ldsXW1; published at B1)
#pragma unroll
    for (int kc = 0; kc < 4; kc++) {
        bf16x8 pa = *(const bf16x8*)&ldsP1[(qh * 32 + l32) * 72 + kc * 16 + half * 8];
#pragma unroll
        for (int nt = 0; nt < 4; nt++) {
            bf16x8 xw = *(const bf16x8*)&ldsXW1[(nh * 128 + nt * 32 + l32) * 72 + kc * 16 + half * 8];
            acc[nt] = __builtin_amdgcn_mfma_f32_32x32x16_bf16(pa, xw, acc[nt], 0, 0, 0);
        }
    }

    // direct quadrant store (each wave owns disjoint 32q x 128n)
    float* Ob = Opart + ((size_t)ksp * B_ + b) * (size_t)L_ * E_
              + (size_t)(qt * 128 + qh * 32) * E_ + nh * 128;
#pragma unroll
    for (int nt = 0; nt < 4; nt++)
#pragma unroll
        for (int r = 0; r < 16; r++) {
            int row = (r & 3) + 8 * (r >> 2) + 4 * half;
            Ob[(size_t)row * E_ + nt * 32 + l32] = acc[nt][r];
        }
}

// ---------------------------------------------------------------------------
// Kernel 5: sum the 2 k-half partials -> fp32 out[B,L,E]
// ---------------------------------------------------------------------------
__global__ void reduce_kernel(const float* __restrict__ Op, float* __restrict__ out) {
    size_t i = ((size_t)blockIdx.x * 256 + threadIdx.x) * 4;
    const size_t BLE = (size_t)B_ * L_ * E_;
    f32x4 a = *(const f32x4*)&Op[i];
    f32x4 c = *(const f32x4*)&Op[BLE + i];
#pragma unroll
    for (int j = 0; j < 4; j++) a[j] += c[j];
    *(f32x4*)&out[i] = a;
}

// ---------------------------------------------------------------------------
extern "C" void kernel_launch(void* const* d_in, const int* in_sizes, int n_in,
                              void* d_out, int out_size, void* d_ws, size_t ws_size,
                              hipStream_t stream) {
    const float* x   = (const float*)d_in[0];
    const float* ipw = (const float*)d_in[1];
    const float* ipb = (const float*)d_in[2];
    const float* wg  = (const float*)d_in[3];
    const float* bg  = (const float*)d_in[4];

    char* ws = (char*)d_ws;
    bf16*  Qs    = (bf16*)(ws);
    bf16*  Ks    = (bf16*)(ws + 8388608);
    bf16*  XWT   = (bf16*)(ws + 16777216);
    float* o     = (float*)(ws + 25165824);
    float* Opart = (float*)(ws + 25427968);
    bf16*  xb    = (bf16*)(ws + 25427968);
    bf16*  Wcat  = (bf16*)(ws + 33816576);

    prep_kernel<<<4864, 256, 0, stream>>>(x, ipw, wg, xb, Wcat);
    proj_kernel<<<dim3(256, 3), 256, 0, stream>>>(xb, Wcat, ipb, bg, Qs, Ks, XWT);
    stats_kernel<<<dim3(16, 4, 8), 256, 0, stream>>>(Qs, Ks, o);
    pass2_kernel<<<256, 512, 0, stream>>>(Qs, Ks, XWT, o, Opart);
    reduce_kernel<<<4096, 256, 0, stream>>>(Opart, (float*)d_out);
}